// Round 16
// baseline (1192.559 us; speedup 1.0000x reference)
//
#include <hip/hip_runtime.h>
#include <math.h>

#define B_   16
#define N_   4096
#define CINF 64
#define M_   1024
#define K_   32
#define C0_  67
#define C1_  64
#define C2_  64
#define C3_  128
#define P_   (B_*M_*K_)      // 524288
#define TP   64              // positions per layer block (R13 proven)
#define POSS 68              // LDS activation row stride
#define WS1  68              // w^T stride for 64-out layers
#define WS3  140             // w^T row stride for 128-out layer (bank-padded)
#define NPB  8192            // layer blocks = P_/TP
#define FTS  68              // featT per-position stride

#define FMA4(A, W, X) \
  A.x = fmaf(W, X.x, A.x); A.y = fmaf(W, X.y, A.y); \
  A.z = fmaf(W, X.z, A.z); A.w = fmaf(W, X.w, A.w);

#define W3OFF(o) ((o) + (((o) >> 5) << 2))

#define DPPF_MAX(G, CTRL) \
  G = fmaxf(G, __int_as_float(__builtin_amdgcn_update_dpp( \
      0, __float_as_int(G), CTRL, 0xf, 0xf, true)));

// ---------------------------------------------------------------- FPS + prep (fused)
// Blocks 0..15: fps. Blocks 16..271: featT prep (hidden under fps shadow).
// R16: winner COORDS ride the reduction spill-free — candidate coords read
// from LDS pre-ladder (latency overlapped), winner extracted via v_readlane
// (SGPR, uniform src), slots carry {key,x,y,z}; post-barrier px[last] re-read
// eliminated. Selections bit-identical (same key order, coords exact copies).
__global__ __launch_bounds__(256) void fps_prep_kernel(
    const float* __restrict__ coords, float* __restrict__ centers,
    const float* __restrict__ features, float* __restrict__ featT, int doPrep) {
  const int t = threadIdx.x;
  if (blockIdx.x >= B_) {
    if (!doPrep) return;
    const int idx = blockIdx.x - B_;
    const int b = idx >> 4;
    const int n = (idx & 15) * 256 + t;
    float* dst = featT + ((size_t)b * N_ + n) * FTS;
    dst[0] = coords[(size_t)b * 3 * N_ + n];
    dst[1] = coords[(size_t)b * 3 * N_ + N_ + n];
    dst[2] = coords[(size_t)b * 3 * N_ + 2 * N_ + n];
#pragma unroll 8
    for (int c = 0; c < CINF; c++) dst[3 + c] = features[((size_t)b * CINF + c) * N_ + n];
    return;
  }
  __shared__ float px[N_], py[N_], pz[N_];
  __shared__ float cxb[M_], cyb[M_], czb[M_];
  __shared__ unsigned long long sk[2][4];
  __shared__ float sxs[2][4], sys[2][4], szs[2][4];
  const int b = blockIdx.x;
  const int wv = t >> 6;
  const int lane = t & 63;
  const float* cb = coords + (size_t)b * 3 * N_;
  for (int i = t; i < N_; i += 256) {
    px[i] = cb[i]; py[i] = cb[N_ + i]; pz[i] = cb[2 * N_ + i];
  }
  __syncthreads();
  float2 x2[8], y2[8], z2[8], mind2[8];
#pragma unroll
  for (int e = 0; e < 8; e++) {
    const int p = t * 16 + 2 * e;
    x2[e] = make_float2(px[p], px[p + 1]);
    y2[e] = make_float2(py[p], py[p + 1]);
    z2[e] = make_float2(pz[p], pz[p + 1]);
    mind2[e] = make_float2(1e10f, 1e10f);
  }
  float cx = px[0], cy = py[0], cz = pz[0];
  for (int i = 0; i < M_; i++) {
    if (t == 0) { cxb[i] = cx; cyb[i] = cy; czb[i] = cz; }
    float bv = -1.0f;
    int bj = 0;
#pragma unroll
    for (int e = 0; e < 8; e++) {
      float2 dx, dy, dz, sx, sy, sz, s, dd;
      dx.x = __fsub_rn(x2[e].x, cx); dx.y = __fsub_rn(x2[e].y, cx);
      dy.x = __fsub_rn(y2[e].x, cy); dy.y = __fsub_rn(y2[e].y, cy);
      dz.x = __fsub_rn(z2[e].x, cz); dz.y = __fsub_rn(z2[e].y, cz);
      sx.x = __fmul_rn(dx.x, dx.x); sx.y = __fmul_rn(dx.y, dx.y);
      sy.x = __fmul_rn(dy.x, dy.x); sy.y = __fmul_rn(dy.y, dy.y);
      sz.x = __fmul_rn(dz.x, dz.x); sz.y = __fmul_rn(dz.y, dz.y);
      s.x = __fadd_rn(sx.x, sy.x); s.y = __fadd_rn(sx.y, sy.y);
      dd.x = __fadd_rn(s.x, sz.x); dd.y = __fadd_rn(s.y, sz.y);
      mind2[e].x = fminf(mind2[e].x, dd.x);
      mind2[e].y = fminf(mind2[e].y, dd.y);
      if (mind2[e].x > bv) { bv = mind2[e].x; bj = 2 * e; }      // strict >
      if (mind2[e].y > bv) { bv = mind2[e].y; bj = 2 * e + 1; }  // keeps first j
    }
    // candidate coords: LDS reads issued EARLY, latency hidden under DPP ladder
    const int cidx = t * 16 + bj;
    const float ox = px[cidx], oy = py[cidx], oz = pz[cidx];
    float g = bv;
    DPPF_MAX(g, 0x111) DPPF_MAX(g, 0x112) DPPF_MAX(g, 0x114) DPPF_MAX(g, 0x118)
    DPPF_MAX(g, 0x142) DPPF_MAX(g, 0x143)
    const float wgv =
        __int_as_float(__builtin_amdgcn_readlane(__float_as_int(g), 63));
    const unsigned long long mk = __ballot(bv == wgv);
    const int src = __ffsll(mk) - 1;
    const int widx = __builtin_amdgcn_readlane(cidx, src);
    const float wx = __int_as_float(__builtin_amdgcn_readlane(__float_as_int(ox), src));
    const float wy = __int_as_float(__builtin_amdgcn_readlane(__float_as_int(oy), src));
    const float wz = __int_as_float(__builtin_amdgcn_readlane(__float_as_int(oz), src));
    const unsigned long long key =
        ((unsigned long long)__float_as_uint(wgv) << 32) | (unsigned)(~widx);
    const int par = i & 1;
    if (lane == 0) { sk[par][wv] = key; sxs[par][wv] = wx; sys[par][wv] = wy; szs[par][wv] = wz; }
    __syncthreads();
    // 4-slot select tree carrying coords (no post-barrier px[last] re-read)
    const unsigned long long k0 = sk[par][0], k1 = sk[par][1];
    const unsigned long long k2 = sk[par][2], k3 = sk[par][3];
    const bool sA = k1 > k0;
    const unsigned long long kA = sA ? k1 : k0;
    const float xA = sA ? sxs[par][1] : sxs[par][0];
    const float yA = sA ? sys[par][1] : sys[par][0];
    const float zA = sA ? szs[par][1] : szs[par][0];
    const bool sB = k3 > k2;
    const unsigned long long kB = sB ? k3 : k2;
    const float xB = sB ? sxs[par][3] : sxs[par][2];
    const float yB = sB ? sys[par][3] : sys[par][2];
    const float zB = sB ? szs[par][3] : szs[par][2];
    const bool sC = kB > kA;
    cx = sC ? xB : xA; cy = sC ? yB : yA; cz = sC ? zB : zA;
  }
  __syncthreads();
  float* cout = centers + (size_t)b * 3 * M_;
  for (int i = t; i < M_; i += 256) {
    cout[i] = cxb[i]; cout[M_ + i] = cyb[i]; cout[2 * M_ + i] = czb[i];
  }
}

// ---------------------------------------------------------------- ball query
// PROVEN R6. Do not touch.
__global__ __launch_bounds__(256) void ballq_kernel(const float* __restrict__ coords,
                                                    const float* __restrict__ centers,
                                                    int* __restrict__ nidx) {
  __shared__ int nb[4][K_];
  const int wid = threadIdx.x >> 6, lane = threadIdx.x & 63;
  const int cid = blockIdx.x * 4 + wid;
  const int b = cid >> 10, m = cid & (M_ - 1);
  const float* cb = coords + (size_t)b * 3 * N_;
  const float cx = centers[(size_t)b * 3 * M_ + m];
  const float cy = centers[(size_t)b * 3 * M_ + M_ + m];
  const float cz = centers[(size_t)b * 3 * M_ + 2 * M_ + m];
  const float cn2 = __fadd_rn(__fadd_rn(__fmul_rn(cx, cx), __fmul_rn(cy, cy)), __fmul_rn(cz, cz));
  int filled = 0;
  for (int ch = 0; ch < N_ / 64 && filled < K_; ch++) {
    const int n = ch * 64 + lane;
    const float x = cb[n], y = cb[N_ + n], z = cb[2 * N_ + n];
    const float pn2 = __fadd_rn(__fadd_rn(__fmul_rn(x, x), __fmul_rn(y, y)), __fmul_rn(z, z));
    const float dot = fmaf(cz, z, fmaf(cy, y, __fmul_rn(cx, x)));
    const float d2 = __fsub_rn(__fadd_rn(cn2, pn2), __fmul_rn(2.0f, dot));
    const bool pass = d2 < 0.04f;
    unsigned long long mk = __ballot(pass);
    int before = __popcll(mk & ((1ull << lane) - 1ull));
    int slot = filled + before;
    if (pass && slot < K_) nb[wid][slot] = n;
    filled += (int)__popcll(mk);
  }
  __syncthreads();
  const int nf = filled < K_ ? filled : K_;
  if (lane < K_) {
    int v = lane < nf ? nb[wid][lane] : (nf > 0 ? nb[wid][0] : 0);
    nidx[(size_t)cid * K_ + lane] = v;
  }
}

// ---------------------------------------------------------------- layer kernels (R13 proven; R16: float2 stats tree -> 4 blocks/CU)
// k1: featT gather -> y1 raw; stats1; store y1.
__global__ __launch_bounds__(256) void layer1_kernel(
    const float* __restrict__ featT, const int* __restrict__ nidx,
    const float* __restrict__ centers,
    const float* __restrict__ w1, const float* __restrict__ b1,
    float2* __restrict__ partials, float* __restrict__ ybuf) {
  __shared__ __align__(16) float a0[C0_ * POSS];
  __shared__ __align__(16) float wT[C0_ * WS1];
  __shared__ __align__(16) float2 red[256];
  const int t = threadIdx.x, bid = blockIdx.x;
  const int p0 = bid * TP;
  const int lane = t & 63, wv = t >> 6;
  {
    const int pos = t >> 2, q = t & 3;
    const int p = p0 + pos;
    const int g = p >> 5;
    const int b = g >> 10, m = g & 1023;
    const int n = nidx[p];
    const float* src = featT + ((size_t)b * N_ + n) * FTS;
    if (q == 0) {
      a0[0 * POSS + pos] = __fsub_rn(src[0], centers[(size_t)b * 3 * M_ + m]);
      a0[1 * POSS + pos] = __fsub_rn(src[1], centers[(size_t)b * 3 * M_ + M_ + m]);
      a0[2 * POSS + pos] = __fsub_rn(src[2], centers[(size_t)b * 3 * M_ + 2 * M_ + m]);
#pragma unroll
      for (int j = 3; j < 17; j++) a0[j * POSS + pos] = src[j];
    } else if (q == 1) {
#pragma unroll
      for (int j = 0; j < 17; j++) a0[(17 + j) * POSS + pos] = src[17 + j];
    } else if (q == 2) {
#pragma unroll
      for (int j = 0; j < 17; j++) a0[(34 + j) * POSS + pos] = src[34 + j];
    } else {
#pragma unroll
      for (int j = 0; j < 16; j++) a0[(51 + j) * POSS + pos] = src[51 + j];
    }
  }
  for (int i = t; i < C1_ * C0_; i += 256) {
    int o = i / C0_, c = i - o * C0_;
    wT[c * WS1 + o] = w1[i];
  }
  __syncthreads();
  const int o0 = (t & 15) * 4;
  const int q0 = (t >> 4) * 4;
  float4 acc[4];
#pragma unroll
  for (int j = 0; j < 4; j++) acc[j] = make_float4(0.f, 0.f, 0.f, 0.f);
  for (int c = 0; c < C0_; c++) {
    const float4 wa = *(const float4*)&wT[c * WS1 + o0];
    const float4 xv = *(const float4*)&a0[c * POSS + q0];
    FMA4(acc[0], wa.x, xv) FMA4(acc[1], wa.y, xv) FMA4(acc[2], wa.z, xv) FMA4(acc[3], wa.w, xv)
  }
  float y_[4][4];
#pragma unroll
  for (int j = 0; j < 4; j++) {
    const float bj = b1[o0 + j];
    y_[j][0] = acc[j].x + bj; y_[j][1] = acc[j].y + bj;
    y_[j][2] = acc[j].z + bj; y_[j][3] = acc[j].w + bj;
  }
#pragma unroll
  for (int i = 0; i < 4; i++) {
    *(float4*)&ybuf[(size_t)(p0 + q0 + i) * 64 + o0] =
        make_float4(y_[0][i], y_[1][i], y_[2][i], y_[3][i]);
  }
  double s1[4], s2[4];
#pragma unroll
  for (int j = 0; j < 4; j++) {
    double ya = (double)y_[j][0], yb = (double)y_[j][1];
    double yc = (double)y_[j][2], yd = (double)y_[j][3];
    s1[j] = (ya + yb) + (yc + yd);
    s2[j] = (ya * ya + yb * yb) + (yc * yc + yd * yd);
  }
#pragma unroll
  for (int msk = 16; msk < 64; msk <<= 1) {
#pragma unroll
    for (int j = 0; j < 4; j++) {
      s1[j] += __shfl_xor(s1[j], msk, 64);
      s2[j] += __shfl_xor(s2[j], msk, 64);
    }
  }
  if (lane < 16) {
#pragma unroll
    for (int j = 0; j < 4; j++)
      red[wv * 64 + o0 + j] = make_float2((float)s1[j], (float)s2[j]);
  }
  __syncthreads();
  if (t < 64) {
    float2 r0 = red[t], r1 = red[64 + t], r2 = red[128 + t], r3 = red[192 + t];
    partials[(size_t)bid * 64 + t] =
        make_float2((r0.x + r1.x) + (r2.x + r3.x), (r0.y + r1.y) + (r2.y + r3.y));
  }
}

// k2: load y1 -> BN1+ReLU -> L2 -> stats2; store y2 in place.
__global__ __launch_bounds__(256) void layer2_kernel(
    const float* __restrict__ w2, const float* __restrict__ b2,
    const float* __restrict__ ss, float2* __restrict__ partials,
    float* __restrict__ ybuf) {
  __shared__ __align__(16) float a1[C1_ * POSS];
  __shared__ __align__(16) float wT[C1_ * WS1];
  __shared__ __align__(16) float2 red[256];
  const int t = threadIdx.x, bid = blockIdx.x;
  const int p0 = bid * TP;
  const int lane = t & 63, wv = t >> 6;
  {
    const int pos = t >> 2, q = t & 3;
    const float* src = ybuf + (size_t)(p0 + pos) * 64 + q * 16;
#pragma unroll
    for (int k4 = 0; k4 < 4; k4++) {
      const float4 v = *(const float4*)&src[k4 * 4];
      const int c = q * 16 + k4 * 4;
      a1[(c + 0) * POSS + pos] = fmaxf(fmaf(v.x, ss[c + 0], ss[64 + c + 0]), 0.f);
      a1[(c + 1) * POSS + pos] = fmaxf(fmaf(v.y, ss[c + 1], ss[64 + c + 1]), 0.f);
      a1[(c + 2) * POSS + pos] = fmaxf(fmaf(v.z, ss[c + 2], ss[64 + c + 2]), 0.f);
      a1[(c + 3) * POSS + pos] = fmaxf(fmaf(v.w, ss[c + 3], ss[64 + c + 3]), 0.f);
    }
  }
  for (int i = t; i < C2_ * C1_; i += 256) {
    int o = i >> 6, c = i & 63;
    wT[c * WS1 + o] = w2[i];
  }
  __syncthreads();
  const int o0 = (t & 15) * 4;
  const int q0 = (t >> 4) * 4;
  float4 acc[4];
#pragma unroll
  for (int j = 0; j < 4; j++) acc[j] = make_float4(0.f, 0.f, 0.f, 0.f);
  for (int c = 0; c < C1_; c++) {
    const float4 wa = *(const float4*)&wT[c * WS1 + o0];
    const float4 xv = *(const float4*)&a1[c * POSS + q0];
    FMA4(acc[0], wa.x, xv) FMA4(acc[1], wa.y, xv) FMA4(acc[2], wa.z, xv) FMA4(acc[3], wa.w, xv)
  }
  float y_[4][4];
#pragma unroll
  for (int j = 0; j < 4; j++) {
    const float bj = b2[o0 + j];
    y_[j][0] = acc[j].x + bj; y_[j][1] = acc[j].y + bj;
    y_[j][2] = acc[j].z + bj; y_[j][3] = acc[j].w + bj;
  }
  __syncthreads();  // all reads of ybuf done before overwrite
#pragma unroll
  for (int i = 0; i < 4; i++) {
    *(float4*)&ybuf[(size_t)(p0 + q0 + i) * 64 + o0] =
        make_float4(y_[0][i], y_[1][i], y_[2][i], y_[3][i]);
  }
  double s1[4], s2[4];
#pragma unroll
  for (int j = 0; j < 4; j++) {
    double ya = (double)y_[j][0], yb = (double)y_[j][1];
    double yc = (double)y_[j][2], yd = (double)y_[j][3];
    s1[j] = (ya + yb) + (yc + yd);
    s2[j] = (ya * ya + yb * yb) + (yc * yc + yd * yd);
  }
#pragma unroll
  for (int msk = 16; msk < 64; msk <<= 1) {
#pragma unroll
    for (int j = 0; j < 4; j++) {
      s1[j] += __shfl_xor(s1[j], msk, 64);
      s2[j] += __shfl_xor(s2[j], msk, 64);
    }
  }
  if (lane < 16) {
#pragma unroll
    for (int j = 0; j < 4; j++)
      red[wv * 64 + o0 + j] = make_float2((float)s1[j], (float)s2[j]);
  }
  __syncthreads();
  if (t < 64) {
    float2 r0 = red[t], r1 = red[64 + t], r2 = red[128 + t], r3 = red[192 + t];
    partials[(size_t)bid * 64 + t] =
        make_float2((r0.x + r1.x) + (r2.x + r3.x), (r0.y + r1.y) + (r2.y + r3.y));
  }
}

// k3: load y2 -> BN2+ReLU -> L3 -> stats3 + raw group-max -> out. (R13 proven)
__global__ __launch_bounds__(256) void layer3_kernel(
    const float* __restrict__ w3, const float* __restrict__ b3,
    const float* __restrict__ ss, float2* __restrict__ partials,
    const float* __restrict__ ybuf, float* __restrict__ out) {
  __shared__ __align__(16) float a0[C2_ * POSS];
  __shared__ __align__(16) float wT[C2_ * WS3];
  __shared__ __align__(16) float2 redf[512];
  __shared__ float redm[512];
  const int t = threadIdx.x, bid = blockIdx.x;
  const int p0 = bid * TP;
  const int lane = t & 63, wv = t >> 6;
  {
    const int pos = t >> 2, q = t & 3;
    const float* src = ybuf + (size_t)(p0 + pos) * 64 + q * 16;
#pragma unroll
    for (int k4 = 0; k4 < 4; k4++) {
      const float4 v = *(const float4*)&src[k4 * 4];
      const int c = q * 16 + k4 * 4;
      a0[(c + 0) * POSS + pos] = fmaxf(fmaf(v.x, ss[128 + c + 0], ss[192 + c + 0]), 0.f);
      a0[(c + 1) * POSS + pos] = fmaxf(fmaf(v.y, ss[128 + c + 1], ss[192 + c + 1]), 0.f);
      a0[(c + 2) * POSS + pos] = fmaxf(fmaf(v.z, ss[128 + c + 2], ss[192 + c + 2]), 0.f);
      a0[(c + 3) * POSS + pos] = fmaxf(fmaf(v.w, ss[128 + c + 3], ss[192 + c + 3]), 0.f);
    }
  }
  for (int i = t; i < C3_ * C2_; i += 256) {
    int o = i >> 6, c = i & 63;
    wT[c * WS3 + W3OFF(o)] = w3[i];
  }
  __syncthreads();
  const int o0 = (t & 15) * 8;
  const int q0 = (t >> 4) * 4;
  const int wo = W3OFF(o0);
  float4 acc[8];
#pragma unroll
  for (int j = 0; j < 8; j++) acc[j] = make_float4(0.f, 0.f, 0.f, 0.f);
  for (int c = 0; c < C2_; c++) {
    const float4 wa = *(const float4*)&wT[c * WS3 + wo];
    const float4 wb = *(const float4*)&wT[c * WS3 + wo + 4];
    const float4 xv = *(const float4*)&a0[c * POSS + q0];
    FMA4(acc[0], wa.x, xv) FMA4(acc[1], wa.y, xv) FMA4(acc[2], wa.z, xv) FMA4(acc[3], wa.w, xv)
    FMA4(acc[4], wb.x, xv) FMA4(acc[5], wb.y, xv) FMA4(acc[6], wb.z, xv) FMA4(acc[7], wb.w, xv)
  }
  double s1[8], s2[8];
  float mx[8];
#pragma unroll
  for (int j = 0; j < 8; j++) {
    const float bj = b3[o0 + j];
    const float y0 = acc[j].x + bj, y1 = acc[j].y + bj;
    const float y2 = acc[j].z + bj, y3 = acc[j].w + bj;
    mx[j] = fmaxf(fmaxf(y0, y1), fmaxf(y2, y3));
    double ya = (double)y0, yb = (double)y1, yc = (double)y2, yd = (double)y3;
    s1[j] = (ya + yb) + (yc + yd);
    s2[j] = (ya * ya + yb * yb) + (yc * yc + yd * yd);
  }
#pragma unroll
  for (int msk = 16; msk < 64; msk <<= 1) {
#pragma unroll
    for (int j = 0; j < 8; j++) {
      s1[j] += __shfl_xor(s1[j], msk, 64);
      s2[j] += __shfl_xor(s2[j], msk, 64);
      mx[j] = fmaxf(mx[j], __shfl_xor(mx[j], msk, 64));
    }
  }
  if (lane < 16) {
#pragma unroll
    for (int j = 0; j < 8; j++) {
      redf[wv * 128 + o0 + j] = make_float2((float)s1[j], (float)s2[j]);
      redm[wv * 128 + o0 + j] = mx[j];
    }
  }
  __syncthreads();
  if (t < 128) {
    float2 r0 = redf[t], r1 = redf[128 + t], r2 = redf[256 + t], r3 = redf[384 + t];
    partials[(size_t)bid * 128 + t] =
        make_float2((r0.x + r1.x) + (r2.x + r3.x), (r0.y + r1.y) + (r2.y + r3.y));
  }
  {
    const int g = t >> 7, o = t & 127;
    const float v = fmaxf(redm[(2 * g) * 128 + o], redm[(2 * g + 1) * 128 + o]);
    const int gg = bid * 2 + g;
    const int b = gg >> 10, m = gg & 1023;
    out[(size_t)b * C3_ * M_ + (size_t)o * M_ + m] = v;
  }
}

// ---------------------------------------------------------------- fallback recompute pass (PROVEN R11; small-ws only)
template <int STAGE>
__global__ __launch_bounds__(256) void pass_kernel(
    const float* __restrict__ features, const float* __restrict__ coords,
    const int* __restrict__ nidx, const float* __restrict__ centers,
    const float* __restrict__ w1, const float* __restrict__ b1,
    const float* __restrict__ w2, const float* __restrict__ b2,
    const float* __restrict__ w3, const float* __restrict__ b3,
    const float* __restrict__ ss, float2* __restrict__ partials,
    float* __restrict__ out) {
  __shared__ __align__(16) float a0[C0_ * POSS];
  constexpr int A1SZ = (STAGE >= 2) ? C1_ * POSS : 4;
  __shared__ __align__(16) float a1[A1SZ];
  constexpr int WTSZ = (STAGE >= 3) ? 64 * WS3 : C0_ * WS1;
  __shared__ __align__(16) float wT[WTSZ];
  constexpr int REDSZ = (STAGE == 3) ? 4 : 256;
  __shared__ __align__(16) double2 red[REDSZ];
  constexpr int RFSZ = (STAGE == 3) ? 512 : 4;
  __shared__ __align__(16) float2 redf[RFSZ];
  __shared__ float redm[RFSZ];
  const int t = threadIdx.x, bid = blockIdx.x;
  const int p0 = bid * TP;
  const int lane = t & 63, wv = t >> 6;
  {
    const int pos = t >> 2, q = t & 3;
    const int p = p0 + pos;
    const int g = p >> 5;
    const int b = g >> 10, m = g & 1023;
    const int n = nidx[p];
    const float* fb = features + (size_t)b * CINF * N_ + n;
    if (q == 0) {
      const float* cbp = coords + (size_t)b * 3 * N_ + n;
      a0[0 * POSS + pos] = __fsub_rn(cbp[0], centers[(size_t)b * 3 * M_ + m]);
      a0[1 * POSS + pos] = __fsub_rn(cbp[N_], centers[(size_t)b * 3 * M_ + M_ + m]);
      a0[2 * POSS + pos] = __fsub_rn(cbp[2 * N_], centers[(size_t)b * 3 * M_ + 2 * M_ + m]);
#pragma unroll
      for (int j = 0; j < 14; j++) a0[(3 + j) * POSS + pos] = fb[(size_t)j * N_];
    } else if (q == 1) {
#pragma unroll
      for (int j = 0; j < 17; j++) a0[(17 + j) * POSS + pos] = fb[(size_t)(14 + j) * N_];
    } else if (q == 2) {
#pragma unroll
      for (int j = 0; j < 17; j++) a0[(34 + j) * POSS + pos] = fb[(size_t)(31 + j) * N_];
    } else {
#pragma unroll
      for (int j = 0; j < 16; j++) a0[(51 + j) * POSS + pos] = fb[(size_t)(48 + j) * N_];
    }
  }
  for (int i = t; i < C1_ * C0_; i += 256) {
    int o = i / C0_, c = i - o * C0_;
    wT[c * WS1 + o] = w1[i];
  }
  __syncthreads();
  {
    const int o0 = (t & 15) * 4;
    const int q0 = (t >> 4) * 4;
    float4 acc[4];
#pragma unroll
    for (int j = 0; j < 4; j++) acc[j] = make_float4(0.f, 0.f, 0.f, 0.f);
    for (int c = 0; c < C0_; c++) {
      const float4 wa = *(const float4*)&wT[c * WS1 + o0];
      const float4 xv = *(const float4*)&a0[c * POSS + q0];
      FMA4(acc[0], wa.x, xv) FMA4(acc[1], wa.y, xv) FMA4(acc[2], wa.z, xv) FMA4(acc[3], wa.w, xv)
    }
    if constexpr (STAGE == 1) {
      double s1[4], s2[4];
#pragma unroll
      for (int j = 0; j < 4; j++) {
        const float bj = b1[o0 + j];
        double ya = (double)(acc[j].x + bj), yb = (double)(acc[j].y + bj);
        double yc = (double)(acc[j].z + bj), yd = (double)(acc[j].w + bj);
        s1[j] = (ya + yb) + (yc + yd);
        s2[j] = (ya * ya + yb * yb) + (yc * yc + yd * yd);
      }
#pragma unroll
      for (int msk = 16; msk < 64; msk <<= 1) {
#pragma unroll
        for (int j = 0; j < 4; j++) {
          s1[j] += __shfl_xor(s1[j], msk, 64);
          s2[j] += __shfl_xor(s2[j], msk, 64);
        }
      }
      if (lane < 16) {
#pragma unroll
        for (int j = 0; j < 4; j++) red[wv * 64 + o0 + j] = make_double2(s1[j], s2[j]);
      }
      __syncthreads();
      if (t < 64) {
        double2 r0 = red[t], r1 = red[64 + t], r2 = red[128 + t], r3 = red[192 + t];
        partials[(size_t)bid * 64 + t] =
            make_float2((float)((r0.x + r1.x) + (r2.x + r3.x)),
                        (float)((r0.y + r1.y) + (r2.y + r3.y)));
      }
    } else {
#pragma unroll
      for (int j = 0; j < 4; j++) {
        const float bj = b1[o0 + j];
        const float scj = ss[o0 + j], shj = ss[64 + o0 + j];
        float4 v;
        v.x = fmaxf(fmaf(acc[j].x + bj, scj, shj), 0.f);
        v.y = fmaxf(fmaf(acc[j].y + bj, scj, shj), 0.f);
        v.z = fmaxf(fmaf(acc[j].z + bj, scj, shj), 0.f);
        v.w = fmaxf(fmaf(acc[j].w + bj, scj, shj), 0.f);
        *(float4*)&a1[(o0 + j) * POSS + q0] = v;
      }
    }
  }
  if constexpr (STAGE >= 2) {
    __syncthreads();
    for (int i = t; i < C2_ * C1_; i += 256) {
      int o = i >> 6, c = i & 63;
      wT[c * WS1 + o] = w2[i];
    }
    __syncthreads();
    {
      const int o0 = (t & 15) * 4;
      const int q0 = (t >> 4) * 4;
      float4 acc[4];
#pragma unroll
      for (int j = 0; j < 4; j++) acc[j] = make_float4(0.f, 0.f, 0.f, 0.f);
      for (int c = 0; c < C1_; c++) {
        const float4 wa = *(const float4*)&wT[c * WS1 + o0];
        const float4 xv = *(const float4*)&a1[c * POSS + q0];
        FMA4(acc[0], wa.x, xv) FMA4(acc[1], wa.y, xv) FMA4(acc[2], wa.z, xv) FMA4(acc[3], wa.w, xv)
      }
      if constexpr (STAGE == 2) {
        double s1[4], s2[4];
#pragma unroll
        for (int j = 0; j < 4; j++) {
          const float bj = b2[o0 + j];
          double ya = (double)(acc[j].x + bj), yb = (double)(acc[j].y + bj);
          double yc = (double)(acc[j].z + bj), yd = (double)(acc[j].w + bj);
          s1[j] = (ya + yb) + (yc + yd);
          s2[j] = (ya * ya + yb * yb) + (yc * yc + yd * yd);
        }
#pragma unroll
        for (int msk = 16; msk < 64; msk <<= 1) {
#pragma unroll
          for (int j = 0; j < 4; j++) {
            s1[j] += __shfl_xor(s1[j], msk, 64);
            s2[j] += __shfl_xor(s2[j], msk, 64);
          }
        }
        if (lane < 16) {
#pragma unroll
          for (int j = 0; j < 4; j++) red[wv * 64 + o0 + j] = make_double2(s1[j], s2[j]);
        }
        __syncthreads();
        if (t < 64) {
          double2 r0 = red[t], r1 = red[64 + t], r2 = red[128 + t], r3 = red[192 + t];
          partials[(size_t)bid * 64 + t] =
              make_float2((float)((r0.x + r1.x) + (r2.x + r3.x)),
                          (float)((r0.y + r1.y) + (r2.y + r3.y)));
        }
      } else {
#pragma unroll
        for (int j = 0; j < 4; j++) {
          const float bj = b2[o0 + j];
          const float scj = ss[128 + o0 + j], shj = ss[192 + o0 + j];
          float4 v;
          v.x = fmaxf(fmaf(acc[j].x + bj, scj, shj), 0.f);
          v.y = fmaxf(fmaf(acc[j].y + bj, scj, shj), 0.f);
          v.z = fmaxf(fmaf(acc[j].z + bj, scj, shj), 0.f);
          v.w = fmaxf(fmaf(acc[j].w + bj, scj, shj), 0.f);
          *(float4*)&a0[(o0 + j) * POSS + q0] = v;
        }
      }
    }
  }
  if constexpr (STAGE == 3) {
    __syncthreads();
    for (int i = t; i < C3_ * C2_; i += 256) {
      int o = i >> 6, c = i & 63;
      wT[c * WS3 + W3OFF(o)] = w3[i];
    }
    __syncthreads();
    {
      const int o0 = (t & 15) * 8;
      const int q0 = (t >> 4) * 4;
      const int wo = W3OFF(o0);
      float4 acc[8];
#pragma unroll
      for (int j = 0; j < 8; j++) acc[j] = make_float4(0.f, 0.f, 0.f, 0.f);
      for (int c = 0; c < C2_; c++) {
        const float4 wa = *(const float4*)&wT[c * WS3 + wo];
        const float4 wb = *(const float4*)&wT[c * WS3 + wo + 4];
        const float4 xv = *(const float4*)&a0[c * POSS + q0];
        FMA4(acc[0], wa.x, xv) FMA4(acc[1], wa.y, xv) FMA4(acc[2], wa.z, xv) FMA4(acc[3], wa.w, xv)
        FMA4(acc[4], wb.x, xv) FMA4(acc[5], wb.y, xv) FMA4(acc[6], wb.z, xv) FMA4(acc[7], wb.w, xv)
      }
      double s1[8], s2[8];
      float mx[8];
#pragma unroll
      for (int j = 0; j < 8; j++) {
        const float bj = b3[o0 + j];
        const float y0 = acc[j].x + bj, y1 = acc[j].y + bj;
        const float y2 = acc[j].z + bj, y3 = acc[j].w + bj;
        mx[j] = fmaxf(fmaxf(y0, y1), fmaxf(y2, y3));
        double ya = (double)y0, yb = (double)y1, yc = (double)y2, yd = (double)y3;
        s1[j] = (ya + yb) + (yc + yd);
        s2[j] = (ya * ya + yb * yb) + (yc * yc + yd * yd);
      }
#pragma unroll
      for (int msk = 16; msk < 64; msk <<= 1) {
#pragma unroll
        for (int j = 0; j < 8; j++) {
          s1[j] += __shfl_xor(s1[j], msk, 64);
          s2[j] += __shfl_xor(s2[j], msk, 64);
          mx[j] = fmaxf(mx[j], __shfl_xor(mx[j], msk, 64));
        }
      }
      if (lane < 16) {
#pragma unroll
        for (int j = 0; j < 8; j++) {
          redf[wv * 128 + o0 + j] = make_float2((float)s1[j], (float)s2[j]);
          redm[wv * 128 + o0 + j] = mx[j];
        }
      }
      __syncthreads();
      if (t < 128) {
        float2 r0 = redf[t], r1 = redf[128 + t], r2 = redf[256 + t], r3 = redf[384 + t];
        partials[(size_t)bid * 128 + t] =
            make_float2((r0.x + r1.x) + (r2.x + r3.x), (r0.y + r1.y) + (r2.y + r3.y));
      }
      {
        const int g = t >> 7, o = t & 127;
        const float v = fmaxf(redm[(2 * g) * 128 + o], redm[(2 * g + 1) * 128 + o]);
        const int gg = bid * 2 + g;
        const int b = gg >> 10, m = gg & 1023;
        out[(size_t)b * C3_ * M_ + (size_t)o * M_ + m] = v;
      }
    }
  }
}

// ---------------------------------------------------------------- finalize (proven R10)
__global__ __launch_bounds__(256) void finalize_kernel(float* __restrict__ out,
                                                       const float* __restrict__ ss) {
  const int i = blockIdx.x * 256 + threadIdx.x;
  const int j = (i >> 10) & 127;
  out[i] = fmaxf(fmaf(out[i], ss[256 + j], ss[384 + j]), 0.f);
}

// ---------------------------------------------------------------- stats reduce
template <int COUT>
__global__ __launch_bounds__(256) void reduce_stats(const float2* __restrict__ partials,
                                                    const float* __restrict__ gam,
                                                    const float* __restrict__ bt,
                                                    float* __restrict__ sc,
                                                    float* __restrict__ sh, int n) {
  const int o = blockIdx.x, t = threadIdx.x;
  double s1 = 0.0, s2 = 0.0;
  for (int i = t; i < n; i += 256) {
    float2 v = partials[(size_t)i * COUT + o];
    s1 += (double)v.x;
    s2 += (double)v.y;
  }
#pragma unroll
  for (int off = 32; off; off >>= 1) {
    s1 += __shfl_xor(s1, off, 64);
    s2 += __shfl_xor(s2, off, 64);
  }
  __shared__ double r1[4], r2[4];
  const int lane = t & 63, wv = t >> 6;
  if (lane == 0) { r1[wv] = s1; r2[wv] = s2; }
  __syncthreads();
  if (t == 0) {
    s1 = (r1[0] + r1[1]) + (r1[2] + r1[3]);
    s2 = (r2[0] + r2[1]) + (r2[2] + r2[3]);
    const double mean = s1 / (double)P_;
    const double var = s2 / (double)P_ - mean * mean;
    const double inv = 1.0 / sqrt(var + 1e-5);
    const float scale = (float)(inv * (double)gam[o]);
    sc[o] = scale;
    sh[o] = (float)(-mean * inv * (double)gam[o] + (double)bt[o]);
  }
}

// ---------------------------------------------------------------- launch
extern "C" void kernel_launch(void* const* d_in, const int* in_sizes, int n_in,
                              void* d_out, int out_size, void* d_ws, size_t ws_size,
                              hipStream_t stream) {
  const float* features = (const float*)d_in[0];
  const float* coords   = (const float*)d_in[1];
  const float* w1  = (const float*)d_in[2];
  const float* b1  = (const float*)d_in[3];
  const float* g1  = (const float*)d_in[4];
  const float* bt1 = (const float*)d_in[5];
  const float* w2  = (const float*)d_in[6];
  const float* b2  = (const float*)d_in[7];
  const float* g2  = (const float*)d_in[8];
  const float* bt2 = (const float*)d_in[9];
  const float* w3  = (const float*)d_in[10];
  const float* b3  = (const float*)d_in[11];
  const float* g3  = (const float*)d_in[12];
  const float* bt3 = (const float*)d_in[13];

  float* out = (float*)d_out;
  float* centers = out + (size_t)B_ * C3_ * M_;  // 2097152

  // Layout: nidx 2MB | ss 4KB | partials 8MB | featT 17.8MB | ybuf 134MB (proven R13)
  char* ws = (char*)d_ws;
  int*    nidx     = (int*)ws;
  float*  ss       = (float*)(ws + 2097152);
  float2* partials = (float2*)(ws + 2097152 + 4096);
  float*  featT    = (float*)(ws + 2097152 + 4096 + 8388608);
  float*  ybuf     = (float*)(ws + 2097152 + 4096 + 8388608 + 17825792);
  const size_t needY = 2097152 + 4096 + 8388608 + 17825792 + (size_t)P_ * 64 * 4;
  const bool BIGY = ws_size >= needY;

  fps_prep_kernel<<<B_ + (BIGY ? 256 : 0), 256, 0, stream>>>(
      coords, centers, features, featT, BIGY ? 1 : 0);
  ballq_kernel<<<(B_ * M_) / 4, 256, 0, stream>>>(coords, centers, nidx);

  if (BIGY) {
    layer1_kernel<<<NPB, 256, 0, stream>>>(featT, nidx, centers, w1, b1, partials, ybuf);
    reduce_stats<64><<<64, 256, 0, stream>>>(partials, g1, bt1, ss + 0, ss + 64, NPB);
    layer2_kernel<<<NPB, 256, 0, stream>>>(w2, b2, ss, partials, ybuf);
    reduce_stats<64><<<64, 256, 0, stream>>>(partials, g2, bt2, ss + 128, ss + 192, NPB);
    layer3_kernel<<<NPB, 256, 0, stream>>>(w3, b3, ss, partials, ybuf, out);
    reduce_stats<128><<<128, 256, 0, stream>>>(partials, g3, bt3, ss + 256, ss + 384, NPB);
  } else {
    pass_kernel<1><<<NPB, 256, 0, stream>>>(features, coords, nidx, centers,
                                            w1, b1, w2, b2, w3, b3, ss, partials, out);
    reduce_stats<64><<<64, 256, 0, stream>>>(partials, g1, bt1, ss + 0, ss + 64, NPB);
    pass_kernel<2><<<NPB, 256, 0, stream>>>(features, coords, nidx, centers,
                                            w1, b1, w2, b2, w3, b3, ss, partials, out);
    reduce_stats<64><<<64, 256, 0, stream>>>(partials, g2, bt2, ss + 128, ss + 192, NPB);
    pass_kernel<3><<<NPB, 256, 0, stream>>>(features, coords, nidx, centers,
                                            w1, b1, w2, b2, w3, b3, ss, partials, out);
    reduce_stats<128><<<128, 256, 0, stream>>>(partials, g3, bt3, ss + 256, ss + 384, NPB);
  }
  finalize_kernel<<<(B_ * C3_ * M_) / 256, 256, 0, stream>>>(out, ss);
}

// Round 17
// 1075.552 us; speedup vs baseline: 1.1088x; 1.1088x over previous
//
#include <hip/hip_runtime.h>
#include <math.h>

#define B_   16
#define N_   4096
#define CINF 64
#define M_   1024
#define K_   32
#define C0_  67
#define C1_  64
#define C2_  64
#define C3_  128
#define P_   (B_*M_*K_)      // 524288
#define TP   64              // positions per layer block (R13 proven)
#define POSS 68              // LDS activation row stride
#define WS1  68              // w^T stride for 64-out layers
#define WS3  140             // w^T row stride for 128-out layer (bank-padded)
#define NPB  8192            // layer blocks = P_/TP
#define FTS  68              // featT per-position stride

#define FMA4(A, W, X) \
  A.x = fmaf(W, X.x, A.x); A.y = fmaf(W, X.y, A.y); \
  A.z = fmaf(W, X.z, A.z); A.w = fmaf(W, X.w, A.w);

#define W3OFF(o) ((o) + (((o) >> 5) << 2))

#define DPPF_MAX(G, CTRL) \
  G = fmaxf(G, __int_as_float(__builtin_amdgcn_update_dpp( \
      0, __float_as_int(G), CTRL, 0xf, 0xf, true)));

// ---------------------------------------------------------------- FPS + prep (fused)
// Blocks 0..15: fps (R15 PROVEN 592us — post-barrier px[last] is a same-
// address broadcast = conflict-free; R16's per-lane candidate-coord reads
// caused 32-way bank conflicts and regressed. Do not touch.)
// Blocks 16..271: featT prep tiles hidden under fps's shadow.
__global__ __launch_bounds__(256) void fps_prep_kernel(
    const float* __restrict__ coords, float* __restrict__ centers,
    const float* __restrict__ features, float* __restrict__ featT, int doPrep) {
  const int t = threadIdx.x;
  if (blockIdx.x >= B_) {
    if (!doPrep) return;
    const int idx = blockIdx.x - B_;
    const int b = idx >> 4;
    const int n = (idx & 15) * 256 + t;
    float* dst = featT + ((size_t)b * N_ + n) * FTS;
    dst[0] = coords[(size_t)b * 3 * N_ + n];
    dst[1] = coords[(size_t)b * 3 * N_ + N_ + n];
    dst[2] = coords[(size_t)b * 3 * N_ + 2 * N_ + n];
#pragma unroll 8
    for (int c = 0; c < CINF; c++) dst[3 + c] = features[((size_t)b * CINF + c) * N_ + n];
    return;
  }
  __shared__ float px[N_], py[N_], pz[N_];
  __shared__ float cxb[M_], cyb[M_], czb[M_];
  __shared__ unsigned long long sk[2][4];
  const int b = blockIdx.x;
  const int wv = t >> 6;
  const int lane = t & 63;
  const float* cb = coords + (size_t)b * 3 * N_;
  for (int i = t; i < N_; i += 256) {
    px[i] = cb[i]; py[i] = cb[N_ + i]; pz[i] = cb[2 * N_ + i];
  }
  __syncthreads();
  float2 x2[8], y2[8], z2[8], mind2[8];
#pragma unroll
  for (int e = 0; e < 8; e++) {
    const int p = t * 16 + 2 * e;
    x2[e] = make_float2(px[p], px[p + 1]);
    y2[e] = make_float2(py[p], py[p + 1]);
    z2[e] = make_float2(pz[p], pz[p + 1]);
    mind2[e] = make_float2(1e10f, 1e10f);
  }
  float cx = px[0], cy = py[0], cz = pz[0];
  for (int i = 0; i < M_; i++) {
    if (t == 0) { cxb[i] = cx; cyb[i] = cy; czb[i] = cz; }
    float bv = -1.0f;
    int bj = 0;
#pragma unroll
    for (int e = 0; e < 8; e++) {
      float2 dx, dy, dz, sx, sy, sz, s, dd;
      dx.x = __fsub_rn(x2[e].x, cx); dx.y = __fsub_rn(x2[e].y, cx);
      dy.x = __fsub_rn(y2[e].x, cy); dy.y = __fsub_rn(y2[e].y, cy);
      dz.x = __fsub_rn(z2[e].x, cz); dz.y = __fsub_rn(z2[e].y, cz);
      sx.x = __fmul_rn(dx.x, dx.x); sx.y = __fmul_rn(dx.y, dx.y);
      sy.x = __fmul_rn(dy.x, dy.x); sy.y = __fmul_rn(dy.y, dy.y);
      sz.x = __fmul_rn(dz.x, dz.x); sz.y = __fmul_rn(dz.y, dz.y);
      s.x = __fadd_rn(sx.x, sy.x); s.y = __fadd_rn(sx.y, sy.y);
      dd.x = __fadd_rn(s.x, sz.x); dd.y = __fadd_rn(s.y, sz.y);
      mind2[e].x = fminf(mind2[e].x, dd.x);
      mind2[e].y = fminf(mind2[e].y, dd.y);
      if (mind2[e].x > bv) { bv = mind2[e].x; bj = 2 * e; }      // strict >
      if (mind2[e].y > bv) { bv = mind2[e].y; bj = 2 * e + 1; }  // keeps first j
    }
    float g = bv;
    DPPF_MAX(g, 0x111) DPPF_MAX(g, 0x112) DPPF_MAX(g, 0x114) DPPF_MAX(g, 0x118)
    DPPF_MAX(g, 0x142) DPPF_MAX(g, 0x143)
    const float wgv =
        __int_as_float(__builtin_amdgcn_readlane(__float_as_int(g), 63));
    const unsigned long long mk = __ballot(bv == wgv);
    const int src = __ffsll(mk) - 1;
    const int widx = __builtin_amdgcn_readlane(t * 16 + bj, src);
    const unsigned long long key =
        ((unsigned long long)__float_as_uint(wgv) << 32) | (unsigned)(~widx);
    const int par = i & 1;
    if (lane == 0) sk[par][wv] = key;
    __syncthreads();
    const unsigned long long k0 = sk[par][0], k1 = sk[par][1];
    const unsigned long long k2 = sk[par][2], k3 = sk[par][3];
    unsigned long long ga = k0 > k1 ? k0 : k1;
    const unsigned long long gb = k2 > k3 ? k2 : k3;
    ga = ga > gb ? ga : gb;
    const int last = (int)(~(unsigned)(ga & 0xffffffffull));
    cx = px[last]; cy = py[last]; cz = pz[last];   // broadcast: conflict-free
  }
  __syncthreads();
  float* cout = centers + (size_t)b * 3 * M_;
  for (int i = t; i < M_; i += 256) {
    cout[i] = cxb[i]; cout[M_ + i] = cyb[i]; cout[2 * M_ + i] = czb[i];
  }
}

// ---------------------------------------------------------------- ball query
// PROVEN R6. Do not touch.
__global__ __launch_bounds__(256) void ballq_kernel(const float* __restrict__ coords,
                                                    const float* __restrict__ centers,
                                                    int* __restrict__ nidx) {
  __shared__ int nb[4][K_];
  const int wid = threadIdx.x >> 6, lane = threadIdx.x & 63;
  const int cid = blockIdx.x * 4 + wid;
  const int b = cid >> 10, m = cid & (M_ - 1);
  const float* cb = coords + (size_t)b * 3 * N_;
  const float cx = centers[(size_t)b * 3 * M_ + m];
  const float cy = centers[(size_t)b * 3 * M_ + M_ + m];
  const float cz = centers[(size_t)b * 3 * M_ + 2 * M_ + m];
  const float cn2 = __fadd_rn(__fadd_rn(__fmul_rn(cx, cx), __fmul_rn(cy, cy)), __fmul_rn(cz, cz));
  int filled = 0;
  for (int ch = 0; ch < N_ / 64 && filled < K_; ch++) {
    const int n = ch * 64 + lane;
    const float x = cb[n], y = cb[N_ + n], z = cb[2 * N_ + n];
    const float pn2 = __fadd_rn(__fadd_rn(__fmul_rn(x, x), __fmul_rn(y, y)), __fmul_rn(z, z));
    const float dot = fmaf(cz, z, fmaf(cy, y, __fmul_rn(cx, x)));
    const float d2 = __fsub_rn(__fadd_rn(cn2, pn2), __fmul_rn(2.0f, dot));
    const bool pass = d2 < 0.04f;
    unsigned long long mk = __ballot(pass);
    int before = __popcll(mk & ((1ull << lane) - 1ull));
    int slot = filled + before;
    if (pass && slot < K_) nb[wid][slot] = n;
    filled += (int)__popcll(mk);
  }
  __syncthreads();
  const int nf = filled < K_ ? filled : K_;
  if (lane < K_) {
    int v = lane < nf ? nb[wid][lane] : (nf > 0 ? nb[wid][0] : 0);
    nidx[(size_t)cid * K_ + lane] = v;
  }
}

// ---------------------------------------------------------------- layer kernels (R13 proven + float2 stats trees)
// k1: featT gather -> y1 raw; stats1; store y1.
__global__ __launch_bounds__(256) void layer1_kernel(
    const float* __restrict__ featT, const int* __restrict__ nidx,
    const float* __restrict__ centers,
    const float* __restrict__ w1, const float* __restrict__ b1,
    float2* __restrict__ partials, float* __restrict__ ybuf) {
  __shared__ __align__(16) float a0[C0_ * POSS];
  __shared__ __align__(16) float wT[C0_ * WS1];
  __shared__ __align__(16) float2 red[256];
  const int t = threadIdx.x, bid = blockIdx.x;
  const int p0 = bid * TP;
  const int lane = t & 63, wv = t >> 6;
  {
    const int pos = t >> 2, q = t & 3;
    const int p = p0 + pos;
    const int g = p >> 5;
    const int b = g >> 10, m = g & 1023;
    const int n = nidx[p];
    const float* src = featT + ((size_t)b * N_ + n) * FTS;
    if (q == 0) {
      a0[0 * POSS + pos] = __fsub_rn(src[0], centers[(size_t)b * 3 * M_ + m]);
      a0[1 * POSS + pos] = __fsub_rn(src[1], centers[(size_t)b * 3 * M_ + M_ + m]);
      a0[2 * POSS + pos] = __fsub_rn(src[2], centers[(size_t)b * 3 * M_ + 2 * M_ + m]);
#pragma unroll
      for (int j = 3; j < 17; j++) a0[j * POSS + pos] = src[j];
    } else if (q == 1) {
#pragma unroll
      for (int j = 0; j < 17; j++) a0[(17 + j) * POSS + pos] = src[17 + j];
    } else if (q == 2) {
#pragma unroll
      for (int j = 0; j < 17; j++) a0[(34 + j) * POSS + pos] = src[34 + j];
    } else {
#pragma unroll
      for (int j = 0; j < 16; j++) a0[(51 + j) * POSS + pos] = src[51 + j];
    }
  }
  for (int i = t; i < C1_ * C0_; i += 256) {
    int o = i / C0_, c = i - o * C0_;
    wT[c * WS1 + o] = w1[i];
  }
  __syncthreads();
  const int o0 = (t & 15) * 4;
  const int q0 = (t >> 4) * 4;
  float4 acc[4];
#pragma unroll
  for (int j = 0; j < 4; j++) acc[j] = make_float4(0.f, 0.f, 0.f, 0.f);
  for (int c = 0; c < C0_; c++) {
    const float4 wa = *(const float4*)&wT[c * WS1 + o0];
    const float4 xv = *(const float4*)&a0[c * POSS + q0];
    FMA4(acc[0], wa.x, xv) FMA4(acc[1], wa.y, xv) FMA4(acc[2], wa.z, xv) FMA4(acc[3], wa.w, xv)
  }
  float y_[4][4];
#pragma unroll
  for (int j = 0; j < 4; j++) {
    const float bj = b1[o0 + j];
    y_[j][0] = acc[j].x + bj; y_[j][1] = acc[j].y + bj;
    y_[j][2] = acc[j].z + bj; y_[j][3] = acc[j].w + bj;
  }
#pragma unroll
  for (int i = 0; i < 4; i++) {
    *(float4*)&ybuf[(size_t)(p0 + q0 + i) * 64 + o0] =
        make_float4(y_[0][i], y_[1][i], y_[2][i], y_[3][i]);
  }
  double s1[4], s2[4];
#pragma unroll
  for (int j = 0; j < 4; j++) {
    double ya = (double)y_[j][0], yb = (double)y_[j][1];
    double yc = (double)y_[j][2], yd = (double)y_[j][3];
    s1[j] = (ya + yb) + (yc + yd);
    s2[j] = (ya * ya + yb * yb) + (yc * yc + yd * yd);
  }
#pragma unroll
  for (int msk = 16; msk < 64; msk <<= 1) {
#pragma unroll
    for (int j = 0; j < 4; j++) {
      s1[j] += __shfl_xor(s1[j], msk, 64);
      s2[j] += __shfl_xor(s2[j], msk, 64);
    }
  }
  if (lane < 16) {
#pragma unroll
    for (int j = 0; j < 4; j++)
      red[wv * 64 + o0 + j] = make_float2((float)s1[j], (float)s2[j]);
  }
  __syncthreads();
  if (t < 64) {
    float2 r0 = red[t], r1 = red[64 + t], r2 = red[128 + t], r3 = red[192 + t];
    partials[(size_t)bid * 64 + t] =
        make_float2((r0.x + r1.x) + (r2.x + r3.x), (r0.y + r1.y) + (r2.y + r3.y));
  }
}

// k2: load y1 -> BN1+ReLU -> L2 -> stats2; store y2 in place.
__global__ __launch_bounds__(256) void layer2_kernel(
    const float* __restrict__ w2, const float* __restrict__ b2,
    const float* __restrict__ ss, float2* __restrict__ partials,
    float* __restrict__ ybuf) {
  __shared__ __align__(16) float a1[C1_ * POSS];
  __shared__ __align__(16) float wT[C1_ * WS1];
  __shared__ __align__(16) float2 red[256];
  const int t = threadIdx.x, bid = blockIdx.x;
  const int p0 = bid * TP;
  const int lane = t & 63, wv = t >> 6;
  {
    const int pos = t >> 2, q = t & 3;
    const float* src = ybuf + (size_t)(p0 + pos) * 64 + q * 16;
#pragma unroll
    for (int k4 = 0; k4 < 4; k4++) {
      const float4 v = *(const float4*)&src[k4 * 4];
      const int c = q * 16 + k4 * 4;
      a1[(c + 0) * POSS + pos] = fmaxf(fmaf(v.x, ss[c + 0], ss[64 + c + 0]), 0.f);
      a1[(c + 1) * POSS + pos] = fmaxf(fmaf(v.y, ss[c + 1], ss[64 + c + 1]), 0.f);
      a1[(c + 2) * POSS + pos] = fmaxf(fmaf(v.z, ss[c + 2], ss[64 + c + 2]), 0.f);
      a1[(c + 3) * POSS + pos] = fmaxf(fmaf(v.w, ss[c + 3], ss[64 + c + 3]), 0.f);
    }
  }
  for (int i = t; i < C2_ * C1_; i += 256) {
    int o = i >> 6, c = i & 63;
    wT[c * WS1 + o] = w2[i];
  }
  __syncthreads();
  const int o0 = (t & 15) * 4;
  const int q0 = (t >> 4) * 4;
  float4 acc[4];
#pragma unroll
  for (int j = 0; j < 4; j++) acc[j] = make_float4(0.f, 0.f, 0.f, 0.f);
  for (int c = 0; c < C1_; c++) {
    const float4 wa = *(const float4*)&wT[c * WS1 + o0];
    const float4 xv = *(const float4*)&a1[c * POSS + q0];
    FMA4(acc[0], wa.x, xv) FMA4(acc[1], wa.y, xv) FMA4(acc[2], wa.z, xv) FMA4(acc[3], wa.w, xv)
  }
  float y_[4][4];
#pragma unroll
  for (int j = 0; j < 4; j++) {
    const float bj = b2[o0 + j];
    y_[j][0] = acc[j].x + bj; y_[j][1] = acc[j].y + bj;
    y_[j][2] = acc[j].z + bj; y_[j][3] = acc[j].w + bj;
  }
  __syncthreads();  // all reads of ybuf done before overwrite
#pragma unroll
  for (int i = 0; i < 4; i++) {
    *(float4*)&ybuf[(size_t)(p0 + q0 + i) * 64 + o0] =
        make_float4(y_[0][i], y_[1][i], y_[2][i], y_[3][i]);
  }
  double s1[4], s2[4];
#pragma unroll
  for (int j = 0; j < 4; j++) {
    double ya = (double)y_[j][0], yb = (double)y_[j][1];
    double yc = (double)y_[j][2], yd = (double)y_[j][3];
    s1[j] = (ya + yb) + (yc + yd);
    s2[j] = (ya * ya + yb * yb) + (yc * yc + yd * yd);
  }
#pragma unroll
  for (int msk = 16; msk < 64; msk <<= 1) {
#pragma unroll
    for (int j = 0; j < 4; j++) {
      s1[j] += __shfl_xor(s1[j], msk, 64);
      s2[j] += __shfl_xor(s2[j], msk, 64);
    }
  }
  if (lane < 16) {
#pragma unroll
    for (int j = 0; j < 4; j++)
      red[wv * 64 + o0 + j] = make_float2((float)s1[j], (float)s2[j]);
  }
  __syncthreads();
  if (t < 64) {
    float2 r0 = red[t], r1 = red[64 + t], r2 = red[128 + t], r3 = red[192 + t];
    partials[(size_t)bid * 64 + t] =
        make_float2((r0.x + r1.x) + (r2.x + r3.x), (r0.y + r1.y) + (r2.y + r3.y));
  }
}

// k3: load y2 -> BN2+ReLU -> L3 -> stats3 + raw group-max -> out. (R13 proven)
__global__ __launch_bounds__(256) void layer3_kernel(
    const float* __restrict__ w3, const float* __restrict__ b3,
    const float* __restrict__ ss, float2* __restrict__ partials,
    const float* __restrict__ ybuf, float* __restrict__ out) {
  __shared__ __align__(16) float a0[C2_ * POSS];
  __shared__ __align__(16) float wT[C2_ * WS3];
  __shared__ __align__(16) float2 redf[512];
  __shared__ float redm[512];
  const int t = threadIdx.x, bid = blockIdx.x;
  const int p0 = bid * TP;
  const int lane = t & 63, wv = t >> 6;
  {
    const int pos = t >> 2, q = t & 3;
    const float* src = ybuf + (size_t)(p0 + pos) * 64 + q * 16;
#pragma unroll
    for (int k4 = 0; k4 < 4; k4++) {
      const float4 v = *(const float4*)&src[k4 * 4];
      const int c = q * 16 + k4 * 4;
      a0[(c + 0) * POSS + pos] = fmaxf(fmaf(v.x, ss[128 + c + 0], ss[192 + c + 0]), 0.f);
      a0[(c + 1) * POSS + pos] = fmaxf(fmaf(v.y, ss[128 + c + 1], ss[192 + c + 1]), 0.f);
      a0[(c + 2) * POSS + pos] = fmaxf(fmaf(v.z, ss[128 + c + 2], ss[192 + c + 2]), 0.f);
      a0[(c + 3) * POSS + pos] = fmaxf(fmaf(v.w, ss[128 + c + 3], ss[192 + c + 3]), 0.f);
    }
  }
  for (int i = t; i < C3_ * C2_; i += 256) {
    int o = i >> 6, c = i & 63;
    wT[c * WS3 + W3OFF(o)] = w3[i];
  }
  __syncthreads();
  const int o0 = (t & 15) * 8;
  const int q0 = (t >> 4) * 4;
  const int wo = W3OFF(o0);
  float4 acc[8];
#pragma unroll
  for (int j = 0; j < 8; j++) acc[j] = make_float4(0.f, 0.f, 0.f, 0.f);
  for (int c = 0; c < C2_; c++) {
    const float4 wa = *(const float4*)&wT[c * WS3 + wo];
    const float4 wb = *(const float4*)&wT[c * WS3 + wo + 4];
    const float4 xv = *(const float4*)&a0[c * POSS + q0];
    FMA4(acc[0], wa.x, xv) FMA4(acc[1], wa.y, xv) FMA4(acc[2], wa.z, xv) FMA4(acc[3], wa.w, xv)
    FMA4(acc[4], wb.x, xv) FMA4(acc[5], wb.y, xv) FMA4(acc[6], wb.z, xv) FMA4(acc[7], wb.w, xv)
  }
  double s1[8], s2[8];
  float mx[8];
#pragma unroll
  for (int j = 0; j < 8; j++) {
    const float bj = b3[o0 + j];
    const float y0 = acc[j].x + bj, y1 = acc[j].y + bj;
    const float y2 = acc[j].z + bj, y3 = acc[j].w + bj;
    mx[j] = fmaxf(fmaxf(y0, y1), fmaxf(y2, y3));
    double ya = (double)y0, yb = (double)y1, yc = (double)y2, yd = (double)y3;
    s1[j] = (ya + yb) + (yc + yd);
    s2[j] = (ya * ya + yb * yb) + (yc * yc + yd * yd);
  }
#pragma unroll
  for (int msk = 16; msk < 64; msk <<= 1) {
#pragma unroll
    for (int j = 0; j < 8; j++) {
      s1[j] += __shfl_xor(s1[j], msk, 64);
      s2[j] += __shfl_xor(s2[j], msk, 64);
      mx[j] = fmaxf(mx[j], __shfl_xor(mx[j], msk, 64));
    }
  }
  if (lane < 16) {
#pragma unroll
    for (int j = 0; j < 8; j++) {
      redf[wv * 128 + o0 + j] = make_float2((float)s1[j], (float)s2[j]);
      redm[wv * 128 + o0 + j] = mx[j];
    }
  }
  __syncthreads();
  if (t < 128) {
    float2 r0 = redf[t], r1 = redf[128 + t], r2 = redf[256 + t], r3 = redf[384 + t];
    partials[(size_t)bid * 128 + t] =
        make_float2((r0.x + r1.x) + (r2.x + r3.x), (r0.y + r1.y) + (r2.y + r3.y));
  }
  {
    const int g = t >> 7, o = t & 127;
    const float v = fmaxf(redm[(2 * g) * 128 + o], redm[(2 * g + 1) * 128 + o]);
    const int gg = bid * 2 + g;
    const int b = gg >> 10, m = gg & 1023;
    out[(size_t)b * C3_ * M_ + (size_t)o * M_ + m] = v;
  }
}

// ---------------------------------------------------------------- fallback recompute pass (PROVEN R11; small-ws only)
template <int STAGE>
__global__ __launch_bounds__(256) void pass_kernel(
    const float* __restrict__ features, const float* __restrict__ coords,
    const int* __restrict__ nidx, const float* __restrict__ centers,
    const float* __restrict__ w1, const float* __restrict__ b1,
    const float* __restrict__ w2, const float* __restrict__ b2,
    const float* __restrict__ w3, const float* __restrict__ b3,
    const float* __restrict__ ss, float2* __restrict__ partials,
    float* __restrict__ out) {
  __shared__ __align__(16) float a0[C0_ * POSS];
  constexpr int A1SZ = (STAGE >= 2) ? C1_ * POSS : 4;
  __shared__ __align__(16) float a1[A1SZ];
  constexpr int WTSZ = (STAGE >= 3) ? 64 * WS3 : C0_ * WS1;
  __shared__ __align__(16) float wT[WTSZ];
  constexpr int REDSZ = (STAGE == 3) ? 4 : 256;
  __shared__ __align__(16) double2 red[REDSZ];
  constexpr int RFSZ = (STAGE == 3) ? 512 : 4;
  __shared__ __align__(16) float2 redf[RFSZ];
  __shared__ float redm[RFSZ];
  const int t = threadIdx.x, bid = blockIdx.x;
  const int p0 = bid * TP;
  const int lane = t & 63, wv = t >> 6;
  {
    const int pos = t >> 2, q = t & 3;
    const int p = p0 + pos;
    const int g = p >> 5;
    const int b = g >> 10, m = g & 1023;
    const int n = nidx[p];
    const float* fb = features + (size_t)b * CINF * N_ + n;
    if (q == 0) {
      const float* cbp = coords + (size_t)b * 3 * N_ + n;
      a0[0 * POSS + pos] = __fsub_rn(cbp[0], centers[(size_t)b * 3 * M_ + m]);
      a0[1 * POSS + pos] = __fsub_rn(cbp[N_], centers[(size_t)b * 3 * M_ + M_ + m]);
      a0[2 * POSS + pos] = __fsub_rn(cbp[2 * N_], centers[(size_t)b * 3 * M_ + 2 * M_ + m]);
#pragma unroll
      for (int j = 0; j < 14; j++) a0[(3 + j) * POSS + pos] = fb[(size_t)j * N_];
    } else if (q == 1) {
#pragma unroll
      for (int j = 0; j < 17; j++) a0[(17 + j) * POSS + pos] = fb[(size_t)(14 + j) * N_];
    } else if (q == 2) {
#pragma unroll
      for (int j = 0; j < 17; j++) a0[(34 + j) * POSS + pos] = fb[(size_t)(31 + j) * N_];
    } else {
#pragma unroll
      for (int j = 0; j < 16; j++) a0[(51 + j) * POSS + pos] = fb[(size_t)(48 + j) * N_];
    }
  }
  for (int i = t; i < C1_ * C0_; i += 256) {
    int o = i / C0_, c = i - o * C0_;
    wT[c * WS1 + o] = w1[i];
  }
  __syncthreads();
  {
    const int o0 = (t & 15) * 4;
    const int q0 = (t >> 4) * 4;
    float4 acc[4];
#pragma unroll
    for (int j = 0; j < 4; j++) acc[j] = make_float4(0.f, 0.f, 0.f, 0.f);
    for (int c = 0; c < C0_; c++) {
      const float4 wa = *(const float4*)&wT[c * WS1 + o0];
      const float4 xv = *(const float4*)&a0[c * POSS + q0];
      FMA4(acc[0], wa.x, xv) FMA4(acc[1], wa.y, xv) FMA4(acc[2], wa.z, xv) FMA4(acc[3], wa.w, xv)
    }
    if constexpr (STAGE == 1) {
      double s1[4], s2[4];
#pragma unroll
      for (int j = 0; j < 4; j++) {
        const float bj = b1[o0 + j];
        double ya = (double)(acc[j].x + bj), yb = (double)(acc[j].y + bj);
        double yc = (double)(acc[j].z + bj), yd = (double)(acc[j].w + bj);
        s1[j] = (ya + yb) + (yc + yd);
        s2[j] = (ya * ya + yb * yb) + (yc * yc + yd * yd);
      }
#pragma unroll
      for (int msk = 16; msk < 64; msk <<= 1) {
#pragma unroll
        for (int j = 0; j < 4; j++) {
          s1[j] += __shfl_xor(s1[j], msk, 64);
          s2[j] += __shfl_xor(s2[j], msk, 64);
        }
      }
      if (lane < 16) {
#pragma unroll
        for (int j = 0; j < 4; j++) red[wv * 64 + o0 + j] = make_double2(s1[j], s2[j]);
      }
      __syncthreads();
      if (t < 64) {
        double2 r0 = red[t], r1 = red[64 + t], r2 = red[128 + t], r3 = red[192 + t];
        partials[(size_t)bid * 64 + t] =
            make_float2((float)((r0.x + r1.x) + (r2.x + r3.x)),
                        (float)((r0.y + r1.y) + (r2.y + r3.y)));
      }
    } else {
#pragma unroll
      for (int j = 0; j < 4; j++) {
        const float bj = b1[o0 + j];
        const float scj = ss[o0 + j], shj = ss[64 + o0 + j];
        float4 v;
        v.x = fmaxf(fmaf(acc[j].x + bj, scj, shj), 0.f);
        v.y = fmaxf(fmaf(acc[j].y + bj, scj, shj), 0.f);
        v.z = fmaxf(fmaf(acc[j].z + bj, scj, shj), 0.f);
        v.w = fmaxf(fmaf(acc[j].w + bj, scj, shj), 0.f);
        *(float4*)&a1[(o0 + j) * POSS + q0] = v;
      }
    }
  }
  if constexpr (STAGE >= 2) {
    __syncthreads();
    for (int i = t; i < C2_ * C1_; i += 256) {
      int o = i >> 6, c = i & 63;
      wT[c * WS1 + o] = w2[i];
    }
    __syncthreads();
    {
      const int o0 = (t & 15) * 4;
      const int q0 = (t >> 4) * 4;
      float4 acc[4];
#pragma unroll
      for (int j = 0; j < 4; j++) acc[j] = make_float4(0.f, 0.f, 0.f, 0.f);
      for (int c = 0; c < C1_; c++) {
        const float4 wa = *(const float4*)&wT[c * WS1 + o0];
        const float4 xv = *(const float4*)&a1[c * POSS + q0];
        FMA4(acc[0], wa.x, xv) FMA4(acc[1], wa.y, xv) FMA4(acc[2], wa.z, xv) FMA4(acc[3], wa.w, xv)
      }
      if constexpr (STAGE == 2) {
        double s1[4], s2[4];
#pragma unroll
        for (int j = 0; j < 4; j++) {
          const float bj = b2[o0 + j];
          double ya = (double)(acc[j].x + bj), yb = (double)(acc[j].y + bj);
          double yc = (double)(acc[j].z + bj), yd = (double)(acc[j].w + bj);
          s1[j] = (ya + yb) + (yc + yd);
          s2[j] = (ya * ya + yb * yb) + (yc * yc + yd * yd);
        }
#pragma unroll
        for (int msk = 16; msk < 64; msk <<= 1) {
#pragma unroll
          for (int j = 0; j < 4; j++) {
            s1[j] += __shfl_xor(s1[j], msk, 64);
            s2[j] += __shfl_xor(s2[j], msk, 64);
          }
        }
        if (lane < 16) {
#pragma unroll
          for (int j = 0; j < 4; j++) red[wv * 64 + o0 + j] = make_double2(s1[j], s2[j]);
        }
        __syncthreads();
        if (t < 64) {
          double2 r0 = red[t], r1 = red[64 + t], r2 = red[128 + t], r3 = red[192 + t];
          partials[(size_t)bid * 64 + t] =
              make_float2((float)((r0.x + r1.x) + (r2.x + r3.x)),
                          (float)((r0.y + r1.y) + (r2.y + r3.y)));
        }
      } else {
#pragma unroll
        for (int j = 0; j < 4; j++) {
          const float bj = b2[o0 + j];
          const float scj = ss[128 + o0 + j], shj = ss[192 + o0 + j];
          float4 v;
          v.x = fmaxf(fmaf(acc[j].x + bj, scj, shj), 0.f);
          v.y = fmaxf(fmaf(acc[j].y + bj, scj, shj), 0.f);
          v.z = fmaxf(fmaf(acc[j].z + bj, scj, shj), 0.f);
          v.w = fmaxf(fmaf(acc[j].w + bj, scj, shj), 0.f);
          *(float4*)&a0[(o0 + j) * POSS + q0] = v;
        }
      }
    }
  }
  if constexpr (STAGE == 3) {
    __syncthreads();
    for (int i = t; i < C3_ * C2_; i += 256) {
      int o = i >> 6, c = i & 63;
      wT[c * WS3 + W3OFF(o)] = w3[i];
    }
    __syncthreads();
    {
      const int o0 = (t & 15) * 8;
      const int q0 = (t >> 4) * 4;
      const int wo = W3OFF(o0);
      float4 acc[8];
#pragma unroll
      for (int j = 0; j < 8; j++) acc[j] = make_float4(0.f, 0.f, 0.f, 0.f);
      for (int c = 0; c < C2_; c++) {
        const float4 wa = *(const float4*)&wT[c * WS3 + wo];
        const float4 wb = *(const float4*)&wT[c * WS3 + wo + 4];
        const float4 xv = *(const float4*)&a0[c * POSS + q0];
        FMA4(acc[0], wa.x, xv) FMA4(acc[1], wa.y, xv) FMA4(acc[2], wa.z, xv) FMA4(acc[3], wa.w, xv)
        FMA4(acc[4], wb.x, xv) FMA4(acc[5], wb.y, xv) FMA4(acc[6], wb.z, xv) FMA4(acc[7], wb.w, xv)
      }
      double s1[8], s2[8];
      float mx[8];
#pragma unroll
      for (int j = 0; j < 8; j++) {
        const float bj = b3[o0 + j];
        const float y0 = acc[j].x + bj, y1 = acc[j].y + bj;
        const float y2 = acc[j].z + bj, y3 = acc[j].w + bj;
        mx[j] = fmaxf(fmaxf(y0, y1), fmaxf(y2, y3));
        double ya = (double)y0, yb = (double)y1, yc = (double)y2, yd = (double)y3;
        s1[j] = (ya + yb) + (yc + yd);
        s2[j] = (ya * ya + yb * yb) + (yc * yc + yd * yd);
      }
#pragma unroll
      for (int msk = 16; msk < 64; msk <<= 1) {
#pragma unroll
        for (int j = 0; j < 8; j++) {
          s1[j] += __shfl_xor(s1[j], msk, 64);
          s2[j] += __shfl_xor(s2[j], msk, 64);
          mx[j] = fmaxf(mx[j], __shfl_xor(mx[j], msk, 64));
        }
      }
      if (lane < 16) {
#pragma unroll
        for (int j = 0; j < 8; j++) {
          redf[wv * 128 + o0 + j] = make_float2((float)s1[j], (float)s2[j]);
          redm[wv * 128 + o0 + j] = mx[j];
        }
      }
      __syncthreads();
      if (t < 128) {
        float2 r0 = redf[t], r1 = redf[128 + t], r2 = redf[256 + t], r3 = redf[384 + t];
        partials[(size_t)bid * 128 + t] =
            make_float2((r0.x + r1.x) + (r2.x + r3.x), (r0.y + r1.y) + (r2.y + r3.y));
      }
      {
        const int g = t >> 7, o = t & 127;
        const float v = fmaxf(redm[(2 * g) * 128 + o], redm[(2 * g + 1) * 128 + o]);
        const int gg = bid * 2 + g;
        const int b = gg >> 10, m = gg & 1023;
        out[(size_t)b * C3_ * M_ + (size_t)o * M_ + m] = v;
      }
    }
  }
}

// ---------------------------------------------------------------- finalize (proven R10)
__global__ __launch_bounds__(256) void finalize_kernel(float* __restrict__ out,
                                                       const float* __restrict__ ss) {
  const int i = blockIdx.x * 256 + threadIdx.x;
  const int j = (i >> 10) & 127;
  out[i] = fmaxf(fmaf(out[i], ss[256 + j], ss[384 + j]), 0.f);
}

// ---------------------------------------------------------------- stats reduce
template <int COUT>
__global__ __launch_bounds__(256) void reduce_stats(const float2* __restrict__ partials,
                                                    const float* __restrict__ gam,
                                                    const float* __restrict__ bt,
                                                    float* __restrict__ sc,
                                                    float* __restrict__ sh, int n) {
  const int o = blockIdx.x, t = threadIdx.x;
  double s1 = 0.0, s2 = 0.0;
  for (int i = t; i < n; i += 256) {
    float2 v = partials[(size_t)i * COUT + o];
    s1 += (double)v.x;
    s2 += (double)v.y;
  }
#pragma unroll
  for (int off = 32; off; off >>= 1) {
    s1 += __shfl_xor(s1, off, 64);
    s2 += __shfl_xor(s2, off, 64);
  }
  __shared__ double r1[4], r2[4];
  const int lane = t & 63, wv = t >> 6;
  if (lane == 0) { r1[wv] = s1; r2[wv] = s2; }
  __syncthreads();
  if (t == 0) {
    s1 = (r1[0] + r1[1]) + (r1[2] + r1[3]);
    s2 = (r2[0] + r2[1]) + (r2[2] + r2[3]);
    const double mean = s1 / (double)P_;
    const double var = s2 / (double)P_ - mean * mean;
    const double inv = 1.0 / sqrt(var + 1e-5);
    const float scale = (float)(inv * (double)gam[o]);
    sc[o] = scale;
    sh[o] = (float)(-mean * inv * (double)gam[o] + (double)bt[o]);
  }
}

// ---------------------------------------------------------------- launch
extern "C" void kernel_launch(void* const* d_in, const int* in_sizes, int n_in,
                              void* d_out, int out_size, void* d_ws, size_t ws_size,
                              hipStream_t stream) {
  const float* features = (const float*)d_in[0];
  const float* coords   = (const float*)d_in[1];
  const float* w1  = (const float*)d_in[2];
  const float* b1  = (const float*)d_in[3];
  const float* g1  = (const float*)d_in[4];
  const float* bt1 = (const float*)d_in[5];
  const float* w2  = (const float*)d_in[6];
  const float* b2  = (const float*)d_in[7];
  const float* g2  = (const float*)d_in[8];
  const float* bt2 = (const float*)d_in[9];
  const float* w3  = (const float*)d_in[10];
  const float* b3  = (const float*)d_in[11];
  const float* g3  = (const float*)d_in[12];
  const float* bt3 = (const float*)d_in[13];

  float* out = (float*)d_out;
  float* centers = out + (size_t)B_ * C3_ * M_;  // 2097152

  // Layout: nidx 2MB | ss 4KB | partials 8MB | featT 17.8MB | ybuf 134MB (proven R13)
  char* ws = (char*)d_ws;
  int*    nidx     = (int*)ws;
  float*  ss       = (float*)(ws + 2097152);
  float2* partials = (float2*)(ws + 2097152 + 4096);
  float*  featT    = (float*)(ws + 2097152 + 4096 + 8388608);
  float*  ybuf     = (float*)(ws + 2097152 + 4096 + 8388608 + 17825792);
  const size_t needY = 2097152 + 4096 + 8388608 + 17825792 + (size_t)P_ * 64 * 4;
  const bool BIGY = ws_size >= needY;

  fps_prep_kernel<<<B_ + (BIGY ? 256 : 0), 256, 0, stream>>>(
      coords, centers, features, featT, BIGY ? 1 : 0);
  ballq_kernel<<<(B_ * M_) / 4, 256, 0, stream>>>(coords, centers, nidx);

  if (BIGY) {
    layer1_kernel<<<NPB, 256, 0, stream>>>(featT, nidx, centers, w1, b1, partials, ybuf);
    reduce_stats<64><<<64, 256, 0, stream>>>(partials, g1, bt1, ss + 0, ss + 64, NPB);
    layer2_kernel<<<NPB, 256, 0, stream>>>(w2, b2, ss, partials, ybuf);
    reduce_stats<64><<<64, 256, 0, stream>>>(partials, g2, bt2, ss + 128, ss + 192, NPB);
    layer3_kernel<<<NPB, 256, 0, stream>>>(w3, b3, ss, partials, ybuf, out);
    reduce_stats<128><<<128, 256, 0, stream>>>(partials, g3, bt3, ss + 256, ss + 384, NPB);
  } else {
    pass_kernel<1><<<NPB, 256, 0, stream>>>(features, coords, nidx, centers,
                                            w1, b1, w2, b2, w3, b3, ss, partials, out);
    reduce_stats<64><<<64, 256, 0, stream>>>(partials, g1, bt1, ss + 0, ss + 64, NPB);
    pass_kernel<2><<<NPB, 256, 0, stream>>>(features, coords, nidx, centers,
                                            w1, b1, w2, b2, w3, b3, ss, partials, out);
    reduce_stats<64><<<64, 256, 0, stream>>>(partials, g2, bt2, ss + 128, ss + 192, NPB);
    pass_kernel<3><<<NPB, 256, 0, stream>>>(features, coords, nidx, centers,
                                            w1, b1, w2, b2, w3, b3, ss, partials, out);
    reduce_stats<128><<<128, 256, 0, stream>>>(partials, g3, bt3, ss + 256, ss + 384, NPB);
  }
  finalize_kernel<<<(B_ * C3_ * M_) / 256, 256, 0, stream>>>(out, ss);
}